// Round 1
// baseline (119.866 us; speedup 1.0000x reference)
//
#include <hip/hip_runtime.h>
#include <hip/hip_bf16.h>

// Chamfer distance, both directions, between two 16384-point fp32 clouds.
// d2(p,q) = |x_p|^2 + |y_q|^2 - 2 x_p.y_q  (same expansion as the reference)
// out = mean_p min_q d2 (thresholded) + mean_q min_p d2 (thresholded)

constexpr int P      = 16384;   // points per cloud
constexpr int BLK    = 256;     // threads per block
constexpr int XPT    = 4;       // x points per thread
constexpr int XCHUNK = BLK * XPT;      // 1024 x points per block -> 16 chunks
constexpr int YSPLIT = 16;             // y segments (parallelism)
constexpr int YSEG   = P / YSPLIT;     // 1024 y per segment
constexpr int YTILE  = 256;            // y points staged in LDS per tile

typedef float v2f __attribute__((ext_vector_type(2)));

static __device__ inline v2f splat(float v) { return (v2f){v, v}; }

// ---------------- prep: pad to float4 with precomputed |p|^2 ----------------
__global__ __launch_bounds__(256) void prep_kernel(
    const float* __restrict__ pc1, const float* __restrict__ pc2,
    float4* __restrict__ pad1, float4* __restrict__ pad2)
{
    int gid = blockIdx.x * blockDim.x + threadIdx.x;   // 0 .. 2P-1
    const float* src = (gid < P) ? pc1 : pc2;
    float4*      dst = (gid < P) ? pad1 : pad2;
    int i = (gid < P) ? gid : gid - P;
    float a = src[3 * i + 0];
    float b = src[3 * i + 1];
    float c = src[3 * i + 2];
    dst[i] = make_float4(a, b, c, fmaf(a, a, fmaf(b, b, c * c)));
}

// ---------------- main: per-direction, per-y-segment partial minima ----------
__global__ __launch_bounds__(256) void chamfer_min_kernel(
    const float4* __restrict__ pad1, const float4* __restrict__ pad2,
    float* __restrict__ partial)   // [2][YSPLIT][P]
{
    const int dir = blockIdx.z;
    const float4* xs = dir ? pad2 : pad1;
    const float4* ys = dir ? pad1 : pad2;
    float* pout = partial + (size_t)dir * YSPLIT * P + (size_t)blockIdx.y * P;

    const int p0 = blockIdx.x * XCHUNK + threadIdx.x;   // strided by BLK for coalescing
    const float4 xA = xs[p0];
    const float4 xB = xs[p0 + BLK];
    const float4 xC = xs[p0 + 2 * BLK];
    const float4 xD = xs[p0 + 3 * BLK];

    // pack (A,B) and (C,D) componentwise into float2 lanes -> v_pk_* candidates
    const v2f x0ab = {xA.x, xB.x}, x1ab = {xA.y, xB.y}, x2ab = {xA.z, xB.z}, xsab = {xA.w, xB.w};
    const v2f x0cd = {xC.x, xD.x}, x1cd = {xC.y, xD.y}, x2cd = {xC.z, xD.z}, xscd = {xC.w, xD.w};

    v2f mab = splat(3.0e38f);
    v2f mcd = splat(3.0e38f);

    __shared__ float4 yt[YTILE];
    const int ybase = blockIdx.y * YSEG;

    for (int t = 0; t < YSEG; t += YTILE) {
        __syncthreads();                       // previous tile fully consumed
        yt[threadIdx.x] = ys[ybase + t + threadIdx.x];
        __syncthreads();

        #pragma unroll 8
        for (int j = 0; j < YTILE; ++j) {
            const float4 y = yt[j];            // same addr across wave: LDS broadcast
            const v2f y0 = splat(y.x), y1 = splat(y.y), y2 = splat(y.z), yw = splat(y.w);

            v2f tab = x0ab * y0;
            tab = __builtin_elementwise_fma(x1ab, y1, tab);
            tab = __builtin_elementwise_fma(x2ab, y2, tab);
            v2f dab = __builtin_elementwise_fma(splat(-2.0f), tab, xsab) + yw;
            mab = __builtin_elementwise_min(mab, dab);

            v2f tcd = x0cd * y0;
            tcd = __builtin_elementwise_fma(x1cd, y1, tcd);
            tcd = __builtin_elementwise_fma(x2cd, y2, tcd);
            v2f dcd = __builtin_elementwise_fma(splat(-2.0f), tcd, xscd) + yw;
            mcd = __builtin_elementwise_min(mcd, dcd);
        }
    }

    pout[p0]           = mab.x;
    pout[p0 + BLK]     = mab.y;
    pout[p0 + 2 * BLK] = mcd.x;
    pout[p0 + 3 * BLK] = mcd.y;
}

// ---------------- reduce: min over segments, threshold, mean, atomic sum ----
__global__ __launch_bounds__(256) void reduce_kernel(
    const float* __restrict__ partial, float* __restrict__ out)
{
    int gid = blockIdx.x * blockDim.x + threadIdx.x;   // 0 .. 2P-1
    int dir = (gid >= P) ? 1 : 0;
    int p = gid & (P - 1);
    const float* base = partial + (size_t)dir * YSPLIT * P + p;

    float m = base[0];
    #pragma unroll
    for (int s = 1; s < YSPLIT; ++s) m = fminf(m, base[(size_t)s * P]);

    if (m >= 2.0f) m = 0.0f;                  // DIST_THD mask
    float v = m * (1.0f / (float)P);          // point_reduction mean; N=1

    // wave64 reduce
    #pragma unroll
    for (int off = 32; off > 0; off >>= 1) v += __shfl_down(v, off, 64);

    __shared__ float wsum[BLK / 64];
    int lane = threadIdx.x & 63;
    int wv   = threadIdx.x >> 6;
    if (lane == 0) wsum[wv] = v;
    __syncthreads();
    if (threadIdx.x == 0) {
        float s = wsum[0];
        #pragma unroll
        for (int w = 1; w < BLK / 64; ++w) s += wsum[w];
        atomicAdd(out, s);
    }
}

extern "C" void kernel_launch(void* const* d_in, const int* in_sizes, int n_in,
                              void* d_out, int out_size, void* d_ws, size_t ws_size,
                              hipStream_t stream) {
    const float* pc1 = (const float*)d_in[0];
    const float* pc2 = (const float*)d_in[1];
    float* out = (float*)d_out;

    // d_ws layout: pad1[P] float4 | pad2[P] float4 | partial[2*YSPLIT*P] float
    float4* pad1 = (float4*)d_ws;
    float4* pad2 = pad1 + P;
    float*  partial = (float*)(pad2 + P);

    hipMemsetAsync(d_out, 0, sizeof(float), stream);   // d_ws/d_out are poisoned each call

    prep_kernel<<<(2 * P) / 256, 256, 0, stream>>>(pc1, pc2, pad1, pad2);

    dim3 grid(P / XCHUNK, YSPLIT, 2);                  // 16 x 16 x 2 = 512 blocks
    chamfer_min_kernel<<<grid, BLK, 0, stream>>>(pad1, pad2, partial);

    reduce_kernel<<<(2 * P) / 256, 256, 0, stream>>>(partial, out);
}

// Round 2
// 103.757 us; speedup vs baseline: 1.1553x; 1.1553x over previous
//
#include <hip/hip_runtime.h>
#include <hip/hip_bf16.h>

// Chamfer distance between two (1,16384,3) fp32 clouds.
// Inner score: t = x.y - |y|^2/2  (maximized over y)  =>  d2min = |x|^2 - 2*max_t.
// Packed fp32 (v_pk_fma_f32) with 2 y-points per instruction, x splat in regs.

constexpr int P      = 16384;
constexpr int BLK    = 256;
constexpr int XPT    = 8;               // x points per thread
constexpr int XCHUNK = BLK * XPT;       // 2048 -> 8 x-chunks
constexpr int YSPLIT = 32;              // y segments -> grid 8*32*2 = 512 blocks
constexpr int YSEG   = P / YSPLIT;      // 512 y per segment, staged once in LDS

typedef float v2f __attribute__((ext_vector_type(2)));

static __device__ inline v2f pk_fma(v2f a, v2f b, v2f c) {
    v2f d;
    asm("v_pk_fma_f32 %0, %1, %2, %3" : "=v"(d) : "v"(a), "v"(b), "v"(c));
    return d;
}

// ---------------- main: per-(dir, y-segment) partial max of t ----------------
__global__ __launch_bounds__(BLK) void chamfer_main(
    const float* __restrict__ pc1, const float* __restrict__ pc2,
    float* __restrict__ partial,    // [2][YSPLIT][P] of max_t
    float* __restrict__ out)        // zeroed here (reduce atomicAdds later)
{
    if (blockIdx.x == 0 && blockIdx.y == 0 && blockIdx.z == 0 && threadIdx.x == 0)
        out[0] = 0.0f;

    const int dir = blockIdx.z;
    const float* xs = dir ? pc2 : pc1;
    const float* ys = dir ? pc1 : pc2;

    // ---- stage whole y segment into LDS as SoA (+ precomputed -|y|^2/2) ----
    __shared__ __align__(16) float ytX[YSEG], ytY[YSEG], ytZ[YSEG], ytW[YSEG];
    const int ybase = blockIdx.y * YSEG;
    for (int k = threadIdx.x; k < YSEG; k += BLK) {
        const int q = ybase + k;
        const float a = ys[3 * q], b = ys[3 * q + 1], c = ys[3 * q + 2];
        ytX[k] = a; ytY[k] = b; ytZ[k] = c;
        ytW[k] = -0.5f * fmaf(a, a, fmaf(b, b, c * c));
    }

    // ---- per-thread x points, splat into v2f for packed math ----
    const int p0 = blockIdx.x * XCHUNK + threadIdx.x;
    v2f xs0[XPT], xs1[XPT], xs2[XPT];
    float acc[XPT];
    #pragma unroll
    for (int k = 0; k < XPT; ++k) {
        const int p = p0 + k * BLK;
        const float a = xs[3 * p], b = xs[3 * p + 1], c = xs[3 * p + 2];
        xs0[k] = (v2f){a, a};
        xs1[k] = (v2f){b, b};
        xs2[k] = (v2f){c, c};
        acc[k] = -3.0e38f;
    }
    __syncthreads();

    // ---- inner loop: 2 y per iteration (broadcast ds_read_b64 x4),
    //      per x-point: 3 v_pk_fma_f32 + 1 v_max3_f32 ----
    #pragma unroll 2
    for (int jp = 0; jp < YSEG / 2; ++jp) {
        const v2f y0 = *(const v2f*)&ytX[2 * jp];
        const v2f y1 = *(const v2f*)&ytY[2 * jp];
        const v2f y2 = *(const v2f*)&ytZ[2 * jp];
        const v2f yw = *(const v2f*)&ytW[2 * jp];
        #pragma unroll
        for (int k = 0; k < XPT; ++k) {
            v2f t = pk_fma(xs0[k], y0, yw);
            t = pk_fma(xs1[k], y1, t);
            t = pk_fma(xs2[k], y2, t);
            acc[k] = fmaxf(fmaxf(acc[k], t.x), t.y);   // -> v_max3_f32
        }
    }

    float* pout = partial + ((size_t)dir * YSPLIT + blockIdx.y) * P;
    #pragma unroll
    for (int k = 0; k < XPT; ++k) pout[p0 + k * BLK] = acc[k];
}

// ---------------- reduce: max over segments, d2, threshold, mean, atomic ----
__global__ __launch_bounds__(BLK) void chamfer_reduce(
    const float* __restrict__ partial,
    const float* __restrict__ pc1, const float* __restrict__ pc2,
    float* __restrict__ out)
{
    const int gid = blockIdx.x * BLK + threadIdx.x;   // 0 .. 2P-1
    const int dir = (gid >= P) ? 1 : 0;
    const int p = gid & (P - 1);
    const float* xsrc = dir ? pc2 : pc1;
    const float* base = partial + (size_t)dir * YSPLIT * P + p;

    float M = base[0];
    #pragma unroll
    for (int s = 1; s < YSPLIT; ++s) M = fmaxf(M, base[(size_t)s * P]);

    const float a = xsrc[3 * p], b = xsrc[3 * p + 1], c = xsrc[3 * p + 2];
    const float xx = fmaf(a, a, fmaf(b, b, c * c));
    float d2 = fmaf(-2.0f, M, xx);                    // |x|^2 - 2*max_t
    if (d2 >= 2.0f) d2 = 0.0f;                        // DIST_THD mask
    float v = d2 * (1.0f / (float)P);                 // mean over points; N=1

    #pragma unroll
    for (int off = 32; off > 0; off >>= 1) v += __shfl_down(v, off, 64);

    __shared__ float wsum[BLK / 64];
    const int lane = threadIdx.x & 63;
    const int wv = threadIdx.x >> 6;
    if (lane == 0) wsum[wv] = v;
    __syncthreads();
    if (threadIdx.x == 0) {
        float s = wsum[0];
        #pragma unroll
        for (int w = 1; w < BLK / 64; ++w) s += wsum[w];
        atomicAdd(out, s);
    }
}

extern "C" void kernel_launch(void* const* d_in, const int* in_sizes, int n_in,
                              void* d_out, int out_size, void* d_ws, size_t ws_size,
                              hipStream_t stream) {
    const float* pc1 = (const float*)d_in[0];
    const float* pc2 = (const float*)d_in[1];
    float* out = (float*)d_out;
    float* partial = (float*)d_ws;                     // 2*YSPLIT*P floats = 4 MB

    dim3 grid(P / XCHUNK, YSPLIT, 2);                  // 8 x 32 x 2 = 512 blocks
    chamfer_main<<<grid, BLK, 0, stream>>>(pc1, pc2, partial, out);
    chamfer_reduce<<<(2 * P) / BLK, BLK, 0, stream>>>(partial, pc1, pc2, out);
}

// Round 3
// 99.778 us; speedup vs baseline: 1.2013x; 1.0399x over previous
//
#include <hip/hip_runtime.h>
#include <hip/hip_bf16.h>

// Chamfer distance between two (1,16384,3) fp32 clouds.
// Inner score: t = x.y - |y|^2/2 (maximized over y) => d2min = |x|^2 - 2*max_t.
// Core: 3 v_pk_fma_f32 + 1 v_max3_f32 per (2 y-points x 1 x-point).
// Occupancy-first config: 2048 blocks (8/CU), interleaved LDS y-groups read
// with broadcast ds_read_b128.

constexpr int P      = 16384;
constexpr int BLK    = 256;
constexpr int XPT    = 4;               // x points per thread
constexpr int XCHUNK = BLK * XPT;       // 1024 -> 16 x-chunks
constexpr int YSPLIT = 64;              // y segments -> grid 16*64*2 = 2048 blocks
constexpr int YSEG   = P / YSPLIT;      // 256 y per segment (one LDS stage)
constexpr int NGRP   = YSEG / 2;        // 128 y-pair groups of 8 floats

typedef float v2f __attribute__((ext_vector_type(2)));

static __device__ inline v2f pk_fma(v2f a, v2f b, v2f c) {
    v2f d;
    asm("v_pk_fma_f32 %0, %1, %2, %3" : "=v"(d) : "v"(a), "v"(b), "v"(c));
    return d;
}
static __device__ inline float max3(float a, float b, float c) {
    float d;
    asm("v_max3_f32 %0, %1, %2, %3" : "=v"(d) : "v"(a), "v"(b), "v"(c));
    return d;
}

// ---------------- main: per-(dir, y-segment) partial max of t ----------------
__global__ __launch_bounds__(BLK, 4) void chamfer_main(
    const float* __restrict__ pc1, const float* __restrict__ pc2,
    float* __restrict__ partial,    // [2][YSPLIT][P] of max_t
    float* __restrict__ out)        // zeroed here (reduce atomicAdds later)
{
    if (blockIdx.x == 0 && blockIdx.y == 0 && blockIdx.z == 0 && threadIdx.x == 0)
        out[0] = 0.0f;

    const int dir = blockIdx.z;
    const float* xs = dir ? pc2 : pc1;
    const float* ys = dir ? pc1 : pc2;

    // ---- stage y segment into LDS, interleaved pair-groups:
    //      group g = { x0,x1, y0,y1, z0,z1, w0,w1 }  (w = -|y|^2/2) ----
    __shared__ __align__(16) float yt[NGRP * 8];
    {
        const int j = threadIdx.x;              // one y point per thread (256 = YSEG)
        const int q = blockIdx.y * YSEG + j;
        const float a = ys[3 * q], b = ys[3 * q + 1], c = ys[3 * q + 2];
        const int g = j >> 1, par = j & 1;
        float* gp = &yt[g * 8 + par];
        gp[0] = a;
        gp[2] = b;
        gp[4] = c;
        gp[6] = -0.5f * fmaf(a, a, fmaf(b, b, c * c));
    }

    // ---- per-thread x points, splat into v2f for packed math ----
    const int p0 = blockIdx.x * XCHUNK + threadIdx.x;
    v2f xs0[XPT], xs1[XPT], xs2[XPT];
    float acc[XPT];
    #pragma unroll
    for (int k = 0; k < XPT; ++k) {
        const int p = p0 + k * BLK;
        const float a = xs[3 * p], b = xs[3 * p + 1], c = xs[3 * p + 2];
        xs0[k] = (v2f){a, a};
        xs1[k] = (v2f){b, b};
        xs2[k] = (v2f){c, c};
        acc[k] = -3.0e38f;
    }
    __syncthreads();

    // ---- inner loop: one y-pair group per iter = 2 broadcast ds_read_b128,
    //      then per x-point: 3 v_pk_fma_f32 + 1 v_max3_f32 ----
    const float4* gptr = (const float4*)yt;
    #pragma unroll 2
    for (int g = 0; g < NGRP; ++g) {
        const float4 A = gptr[2 * g];           // x0,x1,y0,y1
        const float4 B = gptr[2 * g + 1];       // z0,z1,w0,w1
        const v2f y0 = {A.x, A.y};
        const v2f y1 = {A.z, A.w};
        const v2f y2 = {B.x, B.y};
        const v2f yw = {B.z, B.w};
        #pragma unroll
        for (int k = 0; k < XPT; ++k) {
            v2f t = pk_fma(xs0[k], y0, yw);
            t = pk_fma(xs1[k], y1, t);
            t = pk_fma(xs2[k], y2, t);
            acc[k] = max3(acc[k], t.x, t.y);
        }
    }

    float* pout = partial + ((size_t)dir * YSPLIT + blockIdx.y) * P;
    #pragma unroll
    for (int k = 0; k < XPT; ++k) pout[p0 + k * BLK] = acc[k];
}

// ---------------- reduce: max over segments, d2, threshold, mean, atomic ----
__global__ __launch_bounds__(BLK) void chamfer_reduce(
    const float* __restrict__ partial,
    const float* __restrict__ pc1, const float* __restrict__ pc2,
    float* __restrict__ out)
{
    const int gid = blockIdx.x * BLK + threadIdx.x;   // 0 .. 2P-1
    const int dir = (gid >= P) ? 1 : 0;
    const int p = gid & (P - 1);
    const float* xsrc = dir ? pc2 : pc1;
    const float* base = partial + (size_t)dir * YSPLIT * P + p;

    float M = base[0];
    #pragma unroll
    for (int s = 1; s < YSPLIT; ++s) M = fmaxf(M, base[(size_t)s * P]);

    const float a = xsrc[3 * p], b = xsrc[3 * p + 1], c = xsrc[3 * p + 2];
    const float xx = fmaf(a, a, fmaf(b, b, c * c));
    float d2 = fmaf(-2.0f, M, xx);                    // |x|^2 - 2*max_t
    if (d2 >= 2.0f) d2 = 0.0f;                        // DIST_THD mask
    float v = d2 * (1.0f / (float)P);                 // mean over points; N=1

    #pragma unroll
    for (int off = 32; off > 0; off >>= 1) v += __shfl_down(v, off, 64);

    __shared__ float wsum[BLK / 64];
    const int lane = threadIdx.x & 63;
    const int wv = threadIdx.x >> 6;
    if (lane == 0) wsum[wv] = v;
    __syncthreads();
    if (threadIdx.x == 0) {
        float s = wsum[0];
        #pragma unroll
        for (int w = 1; w < BLK / 64; ++w) s += wsum[w];
        atomicAdd(out, s);
    }
}

extern "C" void kernel_launch(void* const* d_in, const int* in_sizes, int n_in,
                              void* d_out, int out_size, void* d_ws, size_t ws_size,
                              hipStream_t stream) {
    const float* pc1 = (const float*)d_in[0];
    const float* pc2 = (const float*)d_in[1];
    float* out = (float*)d_out;
    float* partial = (float*)d_ws;                     // 2*YSPLIT*P floats = 8 MB

    dim3 grid(P / XCHUNK, YSPLIT, 2);                  // 16 x 64 x 2 = 2048 blocks
    chamfer_main<<<grid, BLK, 0, stream>>>(pc1, pc2, partial, out);
    chamfer_reduce<<<(2 * P) / BLK, BLK, 0, stream>>>(partial, pc1, pc2, out);
}